// Round 8
// baseline (265.931 us; speedup 1.0000x reference)
//
#include <hip/hip_runtime.h>
#include <hip/hip_bf16.h>

constexpr int Bb = 2, Hh = 32, Ss = 1024, Dd = 64;
constexpr int NBH = Bb * Hh;     // 64

// M-slot indirection for fallback paths.
__device__ __forceinline__ float* m_slot(float* A, float* B, int nplo,
                                         int bh, int p, int np) {
    return (p < nplo) ? A + ((size_t)bh * nplo + p) * 4096
                      : B + ((size_t)bh * (np - nplo) + (p - nplo)) * 4096;
}

// ---------------------------------------------------------------------------
// Phase 1 (new): per (bh,p) segment, one 512-thread block.
//   waves 0-3 (mode 0): h_local scan (zero init, k v^T input) + o_local = q^T h
//   waves 4-7 (mode 1): M scan (identity init) + z = q^T M
// Shared staging of a,b,exp(gk),k,v,q; parity-double-buffered reduction array
// red[2][16][64]: rows 0-7 = a^T h partials (consumed same step), rows 8-15 =
// q^T {h,M} partials (consumed NEXT step -> same single barrier per step).
// o_local -> d_out [B,S,H,D]; z -> zbuf; G,M -> ws.
// ---------------------------------------------------------------------------
template<int SEG, int CH>
__global__ __launch_bounds__(512, 6) void scan_seg2(
    const float* __restrict__ qp, const float* __restrict__ kp,
    const float* __restrict__ vp, const float* __restrict__ ap,
    const float* __restrict__ bp, const float* __restrict__ gkp,
    float* __restrict__ Gbuf, float* __restrict__ Mbuf,
    float* __restrict__ zbuf, float* __restrict__ out)
{
    constexpr int NP = Ss / SEG;
    const int tid  = (int)threadIdx.x;
    const int lane = tid & 63;
    const int wv   = __builtin_amdgcn_readfirstlane(tid >> 6);   // 0..7
    const int mode = wv >> 2;                    // 0 = G, 1 = M
    const int r0   = (wv & 3) << 4;
    const int moff = (wv & 4);
    const int bid  = (int)blockIdx.x;            // bh*NP + p
    const int p    = bid & (NP - 1);
    const int bh   = bid / NP;
    const int b    = bh >> 5, hh = bh & (Hh - 1);
    const size_t segbase = (size_t)bid * (SEG * Dd);

    __shared__ float la[CH * 64], lb[CH * 64], lw_[CH * 64];
    __shared__ float lk[CH * 64], lv[CH * 64], lq[CH * 64];
    __shared__ float red[2][16][64];

    float h[16];
#pragma unroll
    for (int r = 0; r < 16; ++r) h[r] = mode ? ((r0 + r == lane) ? 1.f : 0.f) : 0.f;

    for (int c0 = 0; c0 < SEG; c0 += CH) {
        __syncthreads();                          // prior chunk LDS reads done
        {
            const size_t gb = segbase + (size_t)c0 * 64;
            if (tid < CH * 16) {                  // waves 0-3: a, b, exp(gk)
                ((float4*)la)[tid] = ((const float4*)(ap + gb))[tid];
                ((float4*)lb)[tid] = ((const float4*)(bp + gb))[tid];
                float4 g = ((const float4*)(gkp + gb))[tid], e;
                e.x = __expf(g.x); e.y = __expf(g.y);
                e.z = __expf(g.z); e.w = __expf(g.w);
                ((float4*)lw_)[tid] = e;
            } else {                              // waves 4-7: k, v, q
                const int i2 = tid - CH * 16;
                ((float4*)lk)[i2] = ((const float4*)(kp + gb))[i2];
                ((float4*)lv)[i2] = ((const float4*)(vp + gb))[i2];
                ((float4*)lq)[i2] = ((const float4*)(qp + gb))[i2];
            }
        }
        __syncthreads();                          // staging visible

#pragma unroll
        for (int tl = 0; tl < CH; ++tl) {
            const int t = c0 + tl;
            const int par = t & 1, pe = par ^ 1;
            // ---- partial a^T h over my 16 rows (pre-update h)
            const float4* ar = (const float4*)(la + tl * 64 + r0);
            float s0 = 0.f, s1 = 0.f, s2 = 0.f, s3 = 0.f;
#pragma unroll
            for (int jj = 0; jj < 4; ++jj) {
                const float4 a4 = ar[jj];
                s0 = fmaf(a4.x, h[4*jj+0], s0);
                s1 = fmaf(a4.y, h[4*jj+1], s1);
                s2 = fmaf(a4.z, h[4*jj+2], s2);
                s3 = fmaf(a4.w, h[4*jj+3], s3);
            }
            red[par][wv][lane] = (s0 + s1) + (s2 + s3);
            __syncthreads();                      // the ONLY per-step barrier
            const float ah = (red[par][moff + 0][lane] + red[par][moff + 1][lane]) +
                             (red[par][moff + 2][lane] + red[par][moff + 3][lane]);

            // ---- deferred o_{t-1} / z_{t-1} stores (rows 8..15, parity pe)
            if (t > 0) {
                if (wv == 0) {
                    const float os = (red[pe][8][lane]  + red[pe][9][lane]) +
                                     (red[pe][10][lane] + red[pe][11][lane]);
                    const int s = p * SEG + t - 1;
                    out[(((size_t)b * Ss + s) * Hh + hh) * Dd + lane] = os;
                } else if (wv == 4) {
                    const float zs = (red[pe][12][lane] + red[pe][13][lane]) +
                                     (red[pe][14][lane] + red[pe][15][lane]);
                    zbuf[segbase + (size_t)(t - 1) * 64 + lane] = zs;
                }
            }

            // ---- state update + q partial
            const float4* br = (const float4*)(lb  + tl * 64 + r0);
            const float4* wr = (const float4*)(lw_ + tl * 64 + r0);
            const float4* qr = (const float4*)(lq  + tl * 64 + r0);
            float q0 = 0.f, q1 = 0.f, q2 = 0.f, q3 = 0.f;
            if (mode == 0) {
                const float u = lv[tl * 64 + lane];
                const float4* kr = (const float4*)(lk + tl * 64 + r0);
#pragma unroll
                for (int jj = 0; jj < 4; ++jj) {
                    const float4 b4 = br[jj], k4 = kr[jj], w4 = wr[jj], q4 = qr[jj];
                    h[4*jj+0] = fmaf(w4.x, h[4*jj+0], fmaf(b4.x, ah, k4.x * u));
                    q0 = fmaf(q4.x, h[4*jj+0], q0);
                    h[4*jj+1] = fmaf(w4.y, h[4*jj+1], fmaf(b4.y, ah, k4.y * u));
                    q1 = fmaf(q4.y, h[4*jj+1], q1);
                    h[4*jj+2] = fmaf(w4.z, h[4*jj+2], fmaf(b4.z, ah, k4.z * u));
                    q2 = fmaf(q4.z, h[4*jj+2], q2);
                    h[4*jj+3] = fmaf(w4.w, h[4*jj+3], fmaf(b4.w, ah, k4.w * u));
                    q3 = fmaf(q4.w, h[4*jj+3], q3);
                }
            } else {
#pragma unroll
                for (int jj = 0; jj < 4; ++jj) {
                    const float4 b4 = br[jj], w4 = wr[jj], q4 = qr[jj];
                    h[4*jj+0] = fmaf(w4.x, h[4*jj+0], b4.x * ah);
                    q0 = fmaf(q4.x, h[4*jj+0], q0);
                    h[4*jj+1] = fmaf(w4.y, h[4*jj+1], b4.y * ah);
                    q1 = fmaf(q4.y, h[4*jj+1], q1);
                    h[4*jj+2] = fmaf(w4.z, h[4*jj+2], b4.z * ah);
                    q2 = fmaf(q4.z, h[4*jj+2], q2);
                    h[4*jj+3] = fmaf(w4.w, h[4*jj+3], b4.w * ah);
                    q3 = fmaf(q4.w, h[4*jj+3], q3);
                }
            }
            red[par][8 + wv][lane] = (q0 + q1) + (q2 + q3);
        }
    }

    __syncthreads();                              // tail: t = SEG-1
    {
        const int pe = (SEG - 1) & 1;
        if (wv == 0) {
            const float os = (red[pe][8][lane]  + red[pe][9][lane]) +
                             (red[pe][10][lane] + red[pe][11][lane]);
            const int s = p * SEG + SEG - 1;
            out[(((size_t)b * Ss + s) * Hh + hh) * Dd + lane] = os;
        } else if (wv == 4) {
            const float zs = (red[pe][12][lane] + red[pe][13][lane]) +
                             (red[pe][14][lane] + red[pe][15][lane]);
            zbuf[segbase + (size_t)(SEG - 1) * 64 + lane] = zs;
        }
    }

    float* dst = (mode == 0) ? Gbuf + (size_t)bid * 4096
                             : Mbuf + (size_t)bid * 4096;
#pragma unroll
    for (int r = 0; r < 16; ++r) dst[(r0 + r) * 64 + lane] = h[r];
}

// ---------------------------------------------------------------------------
// Phase 2: SW_p = M_p * SW_{p-1} + G_p, 4 col-blocks per bh.
// XCD-aware mapping: bh = bid & 63, cb = bid >> 6 -> the 4 col-blocks of a bh
// are 64 apart in blockIdx (64 % 8 == 0) -> same XCD -> M fetched once per bh.
// Double-buffered reg-staged M with swizzled LDS placement (round-6 proven).
// ---------------------------------------------------------------------------
template<int NP>
__global__ __launch_bounds__(256) void combine(
    const float* MbufA, const float* MbufB, int nplo, float* __restrict__ Gbuf)
{
    const int bh  = (int)blockIdx.x & (NBH - 1);
    const int cb  = (int)blockIdx.x >> 6;
    const int c0  = cb * 16;
    const int tid = (int)threadIdx.x;
    const int cl  = tid & 15;
    const int c   = c0 + cl;
    const int rg  = tid >> 4;            // 0..15
    const int r0  = rg * 4;
    const int xorv = (rg & 1) << 2;

    __shared__ float4 Ml[2][1024];
    __shared__ __align__(16) float swT[16][68];

    {
        const float* G0 = Gbuf + (size_t)bh * NP * 4096;
        for (int i = tid; i < 1024; i += 256)
            swT[i & 15][i >> 4] = G0[(i >> 4) * 64 + c0 + (i & 15)];
    }

    float4 mreg[4];
    if (NP > 1) {
        const float4* Mp = (const float4*)m_slot((float*)MbufA, (float*)MbufB,
                                                 nplo, bh, 1, NP);
#pragma unroll
        for (int j = 0; j < 4; ++j) mreg[j] = Mp[j * 256 + tid];
    }
    __syncthreads();
#pragma unroll
    for (int j = 0; j < 4; ++j) {
        const int f = j * 256 + tid;
        Ml[0][f ^ ((f >> 4) & 4)] = mreg[j];
    }
    if (NP > 2) {
        const float4* Mp = (const float4*)m_slot((float*)MbufA, (float*)MbufB,
                                                 nplo, bh, 2, NP);
#pragma unroll
        for (int j = 0; j < 4; ++j) mreg[j] = Mp[j * 256 + tid];
    }
    __syncthreads();

    for (int p = 1; p < NP; ++p) {
        const int par = (p - 1) & 1;
        float* Gp = Gbuf + ((size_t)bh * NP + p) * 4096;

        float gacc[4];
#pragma unroll
        for (int r = 0; r < 4; ++r) gacc[r] = Gp[(r0 + r) * 64 + c];

        float accA[4] = {0.f, 0.f, 0.f, 0.f};
        float accB[4] = {0.f, 0.f, 0.f, 0.f};
        const float4* swr = (const float4*)&swT[cl][0];
#pragma unroll
        for (int m4 = 0; m4 < 16; ++m4) {
            const float4 s = swr[m4];
            const int ms = m4 ^ xorv;
#pragma unroll
            for (int r = 0; r < 4; ++r) {
                const float4 m = Ml[par][(r0 + r) * 16 + ms];
                accA[r] = fmaf(m.x, s.x, fmaf(m.y, s.y, accA[r]));
                accB[r] = fmaf(m.z, s.z, fmaf(m.w, s.w, accB[r]));
            }
        }
        __syncthreads();

#pragma unroll
        for (int r = 0; r < 4; ++r) {
            const float val = accA[r] + accB[r] + gacc[r];
            swT[cl][r0 + r] = val;
            Gp[(r0 + r) * 64 + c] = val;
        }
        if (p + 1 < NP) {
#pragma unroll
            for (int j = 0; j < 4; ++j) {
                const int f = j * 256 + tid;
                Ml[par ^ 1][f ^ ((f >> 4) & 4)] = mreg[j];
            }
        }
        if (p + 2 < NP) {
            const float4* Mp = (const float4*)m_slot((float*)MbufA, (float*)MbufB,
                                                     nplo, bh, p + 2, NP);
#pragma unroll
            for (int j = 0; j < 4; ++j) mreg[j] = Mp[j * 256 + tid];
        }
        __syncthreads();
    }
}

// ---------------------------------------------------------------------------
// Phase 3 (new): out[t] += z_t^T SW_{p-1}. One block per (bh, p>=1).
// SW and the z-slice staged in LDS; lane = v (stride-1 reads), z broadcast.
// ---------------------------------------------------------------------------
template<int SEG>
__global__ __launch_bounds__(256) void seg_correct(
    const float* __restrict__ Gbuf, const float* __restrict__ zbuf,
    float* __restrict__ out)
{
    constexpr int NP = Ss / SEG;
    const int bid = (int)blockIdx.x;              // bh*(NP-1) + (p-1)
    const int bh  = bid / (NP - 1);
    const int p   = bid % (NP - 1) + 1;
    const int tid = (int)threadIdx.x;
    const int lane = tid & 63;
    const int w    = tid >> 6;
    const int b = bh >> 5, hh = bh & (Hh - 1);

    __shared__ float SWs[4096];
    __shared__ float zs[SEG * 64];

    const float* sw = Gbuf + ((size_t)bh * NP + p - 1) * 4096;
    const float* zp = zbuf + ((size_t)(bh * NP + p)) * (SEG * 64);
    for (int i = tid; i < 4096; i += 256)
        SWs[i] = sw[i];
    for (int i = tid; i < SEG * 64; i += 256)
        zs[i] = zp[i];
    __syncthreads();

    for (int t = w; t < SEG; t += 4) {
        float a0 = 0.f, a1 = 0.f, a2 = 0.f, a3 = 0.f;
#pragma unroll
        for (int k = 0; k < 64; k += 4) {
            a0 = fmaf(zs[t * 64 + k + 0], SWs[(k + 0) * 64 + lane], a0);
            a1 = fmaf(zs[t * 64 + k + 1], SWs[(k + 1) * 64 + lane], a1);
            a2 = fmaf(zs[t * 64 + k + 2], SWs[(k + 2) * 64 + lane], a2);
            a3 = fmaf(zs[t * 64 + k + 3], SWs[(k + 3) * 64 + lane], a3);
        }
        const int s = p * SEG + t;
        const size_t o = (((size_t)b * Ss + s) * Hh + hh) * Dd + lane;
        out[o] += (a0 + a1) + (a2 + a3);
    }
}

// ---------------------------------------------------------------------------
// FALLBACK kernels (rounds 6/7 proven) for small workspace.
// ---------------------------------------------------------------------------
template<int SEG, int CH>
__global__ __launch_bounds__(512, 6) void scan_seg_fused(
    const float* __restrict__ kp, const float* __restrict__ vp,
    const float* __restrict__ ap, const float* __restrict__ bp,
    const float* __restrict__ gkp,
    float* __restrict__ Gbuf, float* MbufA, float* MbufB, int nplo)
{
    constexpr int NP = Ss / SEG;
    const int tid  = (int)threadIdx.x;
    const int lane = tid & 63;
    const int wv   = __builtin_amdgcn_readfirstlane(tid >> 6);
    const int mode = wv >> 2;
    const int r0   = (wv & 3) << 4;
    const int moff = (wv & 4);
    const int bid  = (int)blockIdx.x;
    const size_t segbase = (size_t)bid * (SEG * Dd);

    __shared__ float la[CH * 64], lb[CH * 64], lw_[CH * 64];
    __shared__ float lk[CH * 64], lv[CH * 64];
    __shared__ float red[2][8][64];

    float h[16];
#pragma unroll
    for (int r = 0; r < 16; ++r) h[r] = mode ? ((r0 + r == lane) ? 1.f : 0.f) : 0.f;

    for (int c0 = 0; c0 < SEG; c0 += CH) {
        __syncthreads();
        {
            const size_t gb = segbase + (size_t)c0 * 64;
            if (tid < CH * 16) {
                ((float4*)la)[tid] = ((const float4*)(ap + gb))[tid];
                ((float4*)lb)[tid] = ((const float4*)(bp + gb))[tid];
                float4 g = ((const float4*)(gkp + gb))[tid], e;
                e.x = __expf(g.x); e.y = __expf(g.y);
                e.z = __expf(g.z); e.w = __expf(g.w);
                ((float4*)lw_)[tid] = e;
            } else {
                const int i2 = tid - CH * 16;
                ((float4*)lk)[i2] = ((const float4*)(kp + gb))[i2];
                ((float4*)lv)[i2] = ((const float4*)(vp + gb))[i2];
            }
        }
        __syncthreads();

#pragma unroll
        for (int tl = 0; tl < CH; ++tl) {
            const int par = (c0 + tl) & 1;
            const float4* ar = (const float4*)(la + tl * 64 + r0);
            float s0 = 0.f, s1 = 0.f, s2 = 0.f, s3 = 0.f;
#pragma unroll
            for (int jj = 0; jj < 4; ++jj) {
                const float4 a4 = ar[jj];
                s0 = fmaf(a4.x, h[4*jj+0], s0);
                s1 = fmaf(a4.y, h[4*jj+1], s1);
                s2 = fmaf(a4.z, h[4*jj+2], s2);
                s3 = fmaf(a4.w, h[4*jj+3], s3);
            }
            red[par][wv][lane] = (s0 + s1) + (s2 + s3);
            __syncthreads();
            const float ah = (red[par][moff + 0][lane] + red[par][moff + 1][lane]) +
                             (red[par][moff + 2][lane] + red[par][moff + 3][lane]);

            const float4* br = (const float4*)(lb  + tl * 64 + r0);
            const float4* wr = (const float4*)(lw_ + tl * 64 + r0);
            if (mode == 0) {
                const float u = lv[tl * 64 + lane];
                const float4* kr = (const float4*)(lk + tl * 64 + r0);
#pragma unroll
                for (int jj = 0; jj < 4; ++jj) {
                    const float4 b4 = br[jj], k4 = kr[jj], w4 = wr[jj];
                    h[4*jj+0] = fmaf(w4.x, h[4*jj+0], fmaf(b4.x, ah, k4.x * u));
                    h[4*jj+1] = fmaf(w4.y, h[4*jj+1], fmaf(b4.y, ah, k4.y * u));
                    h[4*jj+2] = fmaf(w4.z, h[4*jj+2], fmaf(b4.z, ah, k4.z * u));
                    h[4*jj+3] = fmaf(w4.w, h[4*jj+3], fmaf(b4.w, ah, k4.w * u));
                }
            } else {
#pragma unroll
                for (int jj = 0; jj < 4; ++jj) {
                    const float4 b4 = br[jj], w4 = wr[jj];
                    h[4*jj+0] = fmaf(w4.x, h[4*jj+0], b4.x * ah);
                    h[4*jj+1] = fmaf(w4.y, h[4*jj+1], b4.y * ah);
                    h[4*jj+2] = fmaf(w4.z, h[4*jj+2], b4.z * ah);
                    h[4*jj+3] = fmaf(w4.w, h[4*jj+3], b4.w * ah);
                }
            }
        }
    }

    const int p  = bid & (NP - 1);
    const int bh = bid / NP;
    float* dst = (mode == 0) ? Gbuf + (size_t)bid * 4096
                             : m_slot(MbufA, MbufB, nplo, bh, p, NP);
#pragma unroll
    for (int r = 0; r < 16; ++r) dst[(r0 + r) * 64 + lane] = h[r];
}

template<int SEG, int CH>
__global__ __launch_bounds__(256, 6) void scan_out(
    const float* __restrict__ qp, const float* __restrict__ kp,
    const float* __restrict__ vp, const float* __restrict__ ap,
    const float* __restrict__ bp, const float* __restrict__ gkp,
    const float* __restrict__ Gbuf, float* __restrict__ out)
{
    constexpr int NP = Ss / SEG;
    const int tid  = (int)threadIdx.x;
    const int lane = tid & 63;
    const int w    = __builtin_amdgcn_readfirstlane(tid >> 6);
    const int r0   = w << 4;
    const int bid  = (int)blockIdx.x;
    const int p    = bid & (NP - 1);
    const int bh   = bid / NP;
    const int b    = bh >> 5, hh = bh & (Hh - 1);
    const size_t segbase = (size_t)bid * (SEG * Dd);

    __shared__ float la[CH * 64], lb[CH * 64], lw_[CH * 64];
    __shared__ float lk[CH * 64], lv[CH * 64], lq[CH * 64];
    __shared__ float red_a[2][4][64];
    __shared__ float red_o[2][4][64];

    float h[16];
    if (p) {
        const float* sw = Gbuf + (size_t)(bid - 1) * 4096;
#pragma unroll
        for (int r = 0; r < 16; ++r) h[r] = sw[(r0 + r) * 64 + lane];
    } else {
#pragma unroll
        for (int r = 0; r < 16; ++r) h[r] = 0.f;
    }

    for (int c0 = 0; c0 < SEG; c0 += CH) {
        __syncthreads();
        {
            const size_t gb = segbase + (size_t)c0 * 64;
            for (int i = tid; i < CH * 16; i += 256) {
                ((float4*)la)[i] = ((const float4*)(ap + gb))[i];
                ((float4*)lb)[i] = ((const float4*)(bp + gb))[i];
                float4 g = ((const float4*)(gkp + gb))[i], e;
                e.x = __expf(g.x); e.y = __expf(g.y);
                e.z = __expf(g.z); e.w = __expf(g.w);
                ((float4*)lw_)[i] = e;
                ((float4*)lk)[i] = ((const float4*)(kp + gb))[i];
                ((float4*)lv)[i] = ((const float4*)(vp + gb))[i];
                ((float4*)lq)[i] = ((const float4*)(qp + gb))[i];
            }
        }
        __syncthreads();

#pragma unroll
        for (int tl = 0; tl < CH; ++tl) {
            const int t = c0 + tl;
            const int par = t & 1;
            const float4* ar = (const float4*)(la + tl * 64 + r0);
            float s0 = 0.f, s1 = 0.f, s2 = 0.f, s3 = 0.f;
#pragma unroll
            for (int jj = 0; jj < 4; ++jj) {
                const float4 a4 = ar[jj];
                s0 = fmaf(a4.x, h[4*jj+0], s0);
                s1 = fmaf(a4.y, h[4*jj+1], s1);
                s2 = fmaf(a4.z, h[4*jj+2], s2);
                s3 = fmaf(a4.w, h[4*jj+3], s3);
            }
            red_a[par][w][lane] = (s0 + s1) + (s2 + s3);
            __syncthreads();
            const float ah = (red_a[par][0][lane] + red_a[par][1][lane]) +
                             (red_a[par][2][lane] + red_a[par][3][lane]);

            if (w == 0 && t > 0) {
                const int pe = par ^ 1;
                const float os = (red_o[pe][0][lane] + red_o[pe][1][lane]) +
                                 (red_o[pe][2][lane] + red_o[pe][3][lane]);
                const int s = p * SEG + t - 1;
                out[(((size_t)b * Ss + s) * Hh + hh) * Dd + lane] = os;
            }

            const float u = lv[tl * 64 + lane];
            const float4* br = (const float4*)(lb  + tl * 64 + r0);
            const float4* kr = (const float4*)(lk  + tl * 64 + r0);
            const float4* wr = (const float4*)(lw_ + tl * 64 + r0);
            const float4* qr = (const float4*)(lq  + tl * 64 + r0);
            float o0 = 0.f, o1 = 0.f, o2 = 0.f, o3 = 0.f;
#pragma unroll
            for (int jj = 0; jj < 4; ++jj) {
                const float4 b4 = br[jj], k4 = kr[jj], w4 = wr[jj], q4 = qr[jj];
                h[4*jj+0] = fmaf(w4.x, h[4*jj+0], fmaf(b4.x, ah, k4.x * u));
                o0 = fmaf(q4.x, h[4*jj+0], o0);
                h[4*jj+1] = fmaf(w4.y, h[4*jj+1], fmaf(b4.y, ah, k4.y * u));
                o1 = fmaf(q4.y, h[4*jj+1], o1);
                h[4*jj+2] = fmaf(w4.z, h[4*jj+2], fmaf(b4.z, ah, k4.z * u));
                o2 = fmaf(q4.z, h[4*jj+2], o2);
                h[4*jj+3] = fmaf(w4.w, h[4*jj+3], fmaf(b4.w, ah, k4.w * u));
                o3 = fmaf(q4.w, h[4*jj+3], o3);
            }
            red_o[par][w][lane] = (o0 + o1) + (o2 + o3);
        }
    }

    __syncthreads();
    if (w == 0) {
        const int pe = (SEG - 1) & 1;
        const float os = (red_o[pe][0][lane] + red_o[pe][1][lane]) +
                         (red_o[pe][2][lane] + red_o[pe][3][lane]);
        const int s = p * SEG + SEG - 1;
        out[(((size_t)b * Ss + s) * Hh + hh) * Dd + lane] = os;
    }
}

// ---------------------------------------------------------------------------
// Epilogue (unchanged): in-place GroupNorm + correction + gate on d_out.
// ---------------------------------------------------------------------------
__global__ __launch_bounds__(256) void epilogue(
    const float* __restrict__ qp, const float* __restrict__ kp,
    const float* __restrict__ vp, const float* __restrict__ rk,
    const float* __restrict__ gp, const float* __restrict__ sc,
    const float* __restrict__ bi, float* __restrict__ out)
{
    const int lane = (int)(threadIdx.x & 63u);
    const int gid  = (int)blockIdx.x * 4 + (int)(threadIdx.x >> 6);
    const int hh   = gid & (Hh - 1);
    const int bs   = gid >> 5;
    const int b    = bs >> 10;
    const int s    = bs & (Ss - 1);

    const size_t ioff = ((size_t)(b * Hh + hh) * Ss + s) * Dd + lane;
    const float qv = qp[ioff];
    const float kv = kp[ioff];
    const float vv = vp[ioff];
    const float r  = rk[hh * Dd + lane];

    const size_t goff = (size_t)bs * (Hh * Dd) + hh * Dd + lane;
    const float o = out[goff];

    float s1 = o, s2 = o * o, s3 = qv * kv * r;
#pragma unroll
    for (int m = 32; m >= 1; m >>= 1) {
        s1 += __shfl_xor(s1, m, 64);
        s2 += __shfl_xor(s2, m, 64);
        s3 += __shfl_xor(s3, m, 64);
    }
    const float mu  = s1 * (1.f / 64.f);
    const float var = fmaf(-mu, mu, s2 * (1.f / 64.f));
    const float on  = (o - mu) * rsqrtf(var + 1e-5f);

    out[goff] = (fmaf(on, sc[hh * Dd + lane], bi[hh * Dd + lane]) + s3 * vv) * gp[goff];
}

// ---------------------------------------------------------------------------
extern "C" void kernel_launch(void* const* d_in, const int* in_sizes, int n_in,
                              void* d_out, int out_size, void* d_ws, size_t ws_size,
                              hipStream_t stream)
{
    const float* q   = (const float*)d_in[0];
    const float* k   = (const float*)d_in[1];
    const float* v   = (const float*)d_in[2];
    const float* a   = (const float*)d_in[3];
    const float* b   = (const float*)d_in[4];
    const float* gk  = (const float*)d_in[5];
    const float* r_k = (const float*)d_in[6];
    const float* g   = (const float*)d_in[7];
    const float* gns = (const float*)d_in[8];
    const float* gnb = (const float*)d_in[9];
    float* out = (float*)d_out;
    float* ws  = (float*)d_ws;

    // New path: SEG=64, NP=16. ws = G(16.8M) + M(16.8M) + z(16.8M) = 50.3 MB.
    const size_t gN  = (size_t)NBH * 16 * 4096;        // 4.19M floats each
    const size_t need_new = gN * 3 * sizeof(float);
    const size_t g32 = (size_t)NBH * 32 * 4096;
    const size_t need_old32 = g32 * 2 * sizeof(float); // 64 MiB

    if (ws_size >= need_new) {
        float* G = ws;
        float* M = ws + gN;
        float* Z = ws + 2 * gN;
        scan_seg2<64, 16><<<dim3(NBH * 16), dim3(512), 0, stream>>>(
            q, k, v, a, b, gk, G, M, Z, out);
        combine<16><<<dim3(NBH * 4), dim3(256), 0, stream>>>(M, M, 16, G);
        seg_correct<64><<<dim3(NBH * 15), dim3(256), 0, stream>>>(G, Z, out);
    } else if (ws_size >= need_old32) {
        float* G  = ws;
        float* MA = ws + g32;
        scan_seg_fused<32, 16><<<dim3(NBH * 32), dim3(512), 0, stream>>>(
            k, v, a, b, gk, G, MA, MA, 32);
        combine<32><<<dim3(NBH * 4), dim3(256), 0, stream>>>(MA, MA, 32, G);
        scan_out<32, 16><<<dim3(NBH * 32), dim3(256), 0, stream>>>(
            q, k, v, a, b, gk, G, out);
    } else {
        float* G  = ws;
        float* MA = out;
        scan_seg_fused<64, 16><<<dim3(NBH * 16), dim3(512), 0, stream>>>(
            k, v, a, b, gk, G, MA, MA, 16);
        combine<16><<<dim3(NBH * 4), dim3(256), 0, stream>>>(MA, MA, 16, G);
        scan_out<64, 16><<<dim3(NBH * 16), dim3(256), 0, stream>>>(
            q, k, v, a, b, gk, G, out);
    }

    epilogue<<<dim3(Bb * Ss * Hh / 4), dim3(256), 0, stream>>>(
        q, k, v, r_k, g, gns, gnb, out);
}

// Round 9
// 242.185 us; speedup vs baseline: 1.0980x; 1.0980x over previous
//
#include <hip/hip_runtime.h>
#include <hip/hip_bf16.h>

constexpr int Bb = 2, Hh = 32, Ss = 1024, Dd = 64;
constexpr int NBH = Bb * Hh;     // 64

// M-slot indirection for fallback paths.
__device__ __forceinline__ float* m_slot(float* A, float* B, int nplo,
                                         int bh, int p, int np) {
    return (p < nplo) ? A + ((size_t)bh * nplo + p) * 4096
                      : B + ((size_t)bh * (np - nplo) + (p - nplo)) * 4096;
}

// ---------------------------------------------------------------------------
// Phase 1: per (bh,p) segment, one 512-thread block.
//   waves 0-3 (mode 0): h_local scan (zero init, k v^T input) + o_local = q^T h
//   waves 4-7 (mode 1): M scan (identity init) + z = q^T M
// Deferred o/z partial sums are written to LDS ring buffers lo/lz (CH steps)
// and flushed to global as coalesced float4 bursts at chunk boundaries --
// NO global stores inside the per-step barrier loop (vmcnt-drain fix).
// ---------------------------------------------------------------------------
template<int SEG, int CH>
__global__ __launch_bounds__(512, 6) void scan_seg3(
    const float* __restrict__ qp, const float* __restrict__ kp,
    const float* __restrict__ vp, const float* __restrict__ ap,
    const float* __restrict__ bp, const float* __restrict__ gkp,
    float* __restrict__ Gbuf, float* __restrict__ Mbuf,
    float* __restrict__ zbuf, float* __restrict__ out)
{
    constexpr int NP = Ss / SEG;
    const int tid  = (int)threadIdx.x;
    const int lane = tid & 63;
    const int wv   = __builtin_amdgcn_readfirstlane(tid >> 6);   // 0..7
    const int mode = wv >> 2;                    // 0 = G, 1 = M
    const int r0   = (wv & 3) << 4;
    const int moff = (wv & 4);
    const int bid  = (int)blockIdx.x;            // bh*NP + p
    const int p    = bid & (NP - 1);
    const int bh   = bid / NP;
    const int b    = bh >> 5, hh = bh & (Hh - 1);
    const size_t segbase = (size_t)bid * (SEG * Dd);

    __shared__ float la[CH * 64], lb[CH * 64], lw_[CH * 64];
    __shared__ float lk[CH * 64], lv[CH * 64], lq[CH * 64];
    __shared__ float red[2][16][64];
    __shared__ float lo[CH * 64], lz[CH * 64];   // o/z ring buffers

    float h[16];
#pragma unroll
    for (int r = 0; r < 16; ++r) h[r] = mode ? ((r0 + r == lane) ? 1.f : 0.f) : 0.f;

    for (int c0 = 0; c0 < SEG; c0 += CH) {
        __syncthreads();                          // prior chunk LDS reads + lo/lz writes done

        // ---- flush previous chunk's o/z window: steps [c0-CH-1 .. c0-2]
        if (c0 > 0) {
            if (tid < 256) {
                const int j = tid >> 4;           // 0..15
                const int s = c0 - CH - 1 + j;
                if (s >= 0) {
                    const int slot = s & (CH - 1);
                    const float4 vv4 = ((const float4*)lo)[(slot << 4) | (tid & 15)];
                    const size_t o = (((size_t)b * Ss + p * SEG + s) * Hh + hh) * Dd
                                     + ((tid & 15) << 2);
                    *(float4*)(out + o) = vv4;
                }
            } else {
                const int t2 = tid - 256;
                const int j = t2 >> 4;
                const int s = c0 - CH - 1 + j;
                if (s >= 0) {
                    const int slot = s & (CH - 1);
                    const float4 vv4 = ((const float4*)lz)[(slot << 4) | (t2 & 15)];
                    *(float4*)(zbuf + segbase + (size_t)s * 64 + ((t2 & 15) << 2)) = vv4;
                }
            }
        }

        // ---- stage CH steps of the 6 streams
        {
            const size_t gb = segbase + (size_t)c0 * 64;
            if (tid < CH * 16) {                  // threads 0-255: a, b, exp(gk)
                ((float4*)la)[tid] = ((const float4*)(ap + gb))[tid];
                ((float4*)lb)[tid] = ((const float4*)(bp + gb))[tid];
                float4 g = ((const float4*)(gkp + gb))[tid], e;
                e.x = __expf(g.x); e.y = __expf(g.y);
                e.z = __expf(g.z); e.w = __expf(g.w);
                ((float4*)lw_)[tid] = e;
            } else {                              // threads 256-511: k, v, q
                const int i2 = tid - CH * 16;
                ((float4*)lk)[i2] = ((const float4*)(kp + gb))[i2];
                ((float4*)lv)[i2] = ((const float4*)(vp + gb))[i2];
                ((float4*)lq)[i2] = ((const float4*)(qp + gb))[i2];
            }
        }
        __syncthreads();                          // staging visible

#pragma unroll
        for (int tl = 0; tl < CH; ++tl) {
            const int t = c0 + tl;
            const int par = t & 1, pe = par ^ 1;
            // ---- partial a^T h over my 16 rows (pre-update h)
            const float4* ar = (const float4*)(la + tl * 64 + r0);
            float s0 = 0.f, s1 = 0.f, s2 = 0.f, s3 = 0.f;
#pragma unroll
            for (int jj = 0; jj < 4; ++jj) {
                const float4 a4 = ar[jj];
                s0 = fmaf(a4.x, h[4*jj+0], s0);
                s1 = fmaf(a4.y, h[4*jj+1], s1);
                s2 = fmaf(a4.z, h[4*jj+2], s2);
                s3 = fmaf(a4.w, h[4*jj+3], s3);
            }
            red[par][wv][lane] = (s0 + s1) + (s2 + s3);
            __syncthreads();                      // the ONLY per-step barrier
            const float ah = (red[par][moff + 0][lane] + red[par][moff + 1][lane]) +
                             (red[par][moff + 2][lane] + red[par][moff + 3][lane]);

            // ---- deferred o_{t-1} / z_{t-1} -> LDS ring (no global store!)
            if (t > 0) {
                if (wv == 0) {
                    const float os = (red[pe][8][lane]  + red[pe][9][lane]) +
                                     (red[pe][10][lane] + red[pe][11][lane]);
                    lo[((t - 1) & (CH - 1)) * 64 + lane] = os;
                } else if (wv == 4) {
                    const float zs = (red[pe][12][lane] + red[pe][13][lane]) +
                                     (red[pe][14][lane] + red[pe][15][lane]);
                    lz[((t - 1) & (CH - 1)) * 64 + lane] = zs;
                }
            }

            // ---- state update + q partial
            const float4* br = (const float4*)(lb  + tl * 64 + r0);
            const float4* wr = (const float4*)(lw_ + tl * 64 + r0);
            const float4* qr = (const float4*)(lq  + tl * 64 + r0);
            float q0 = 0.f, q1 = 0.f, q2 = 0.f, q3 = 0.f;
            if (mode == 0) {
                const float u = lv[tl * 64 + lane];
                const float4* kr = (const float4*)(lk + tl * 64 + r0);
#pragma unroll
                for (int jj = 0; jj < 4; ++jj) {
                    const float4 b4 = br[jj], k4 = kr[jj], w4 = wr[jj], q4 = qr[jj];
                    h[4*jj+0] = fmaf(w4.x, h[4*jj+0], fmaf(b4.x, ah, k4.x * u));
                    q0 = fmaf(q4.x, h[4*jj+0], q0);
                    h[4*jj+1] = fmaf(w4.y, h[4*jj+1], fmaf(b4.y, ah, k4.y * u));
                    q1 = fmaf(q4.y, h[4*jj+1], q1);
                    h[4*jj+2] = fmaf(w4.z, h[4*jj+2], fmaf(b4.z, ah, k4.z * u));
                    q2 = fmaf(q4.z, h[4*jj+2], q2);
                    h[4*jj+3] = fmaf(w4.w, h[4*jj+3], fmaf(b4.w, ah, k4.w * u));
                    q3 = fmaf(q4.w, h[4*jj+3], q3);
                }
            } else {
#pragma unroll
                for (int jj = 0; jj < 4; ++jj) {
                    const float4 b4 = br[jj], w4 = wr[jj], q4 = qr[jj];
                    h[4*jj+0] = fmaf(w4.x, h[4*jj+0], b4.x * ah);
                    q0 = fmaf(q4.x, h[4*jj+0], q0);
                    h[4*jj+1] = fmaf(w4.y, h[4*jj+1], b4.y * ah);
                    q1 = fmaf(q4.y, h[4*jj+1], q1);
                    h[4*jj+2] = fmaf(w4.z, h[4*jj+2], b4.z * ah);
                    q2 = fmaf(q4.z, h[4*jj+2], q2);
                    h[4*jj+3] = fmaf(w4.w, h[4*jj+3], b4.w * ah);
                    q3 = fmaf(q4.w, h[4*jj+3], q3);
                }
            }
            red[par][8 + wv][lane] = (q0 + q1) + (q2 + q3);
        }
    }

    __syncthreads();                              // last chunk's lo/lz writes done

    // ---- final flush: steps [SEG-CH-1 .. SEG-2]
    if (tid < 256) {
        const int j = tid >> 4;
        const int s = SEG - CH - 1 + j;
        const int slot = s & (CH - 1);
        const float4 vv4 = ((const float4*)lo)[(slot << 4) | (tid & 15)];
        const size_t o = (((size_t)b * Ss + p * SEG + s) * Hh + hh) * Dd
                         + ((tid & 15) << 2);
        *(float4*)(out + o) = vv4;
    } else {
        const int t2 = tid - 256;
        const int j = t2 >> 4;
        const int s = SEG - CH - 1 + j;
        const int slot = s & (CH - 1);
        const float4 vv4 = ((const float4*)lz)[(slot << 4) | (t2 & 15)];
        *(float4*)(zbuf + segbase + (size_t)s * 64 + ((t2 & 15) << 2)) = vv4;
    }

    // ---- tail step SEG-1 directly from red
    {
        const int pe = (SEG - 1) & 1;
        if (wv == 0) {
            const float os = (red[pe][8][lane]  + red[pe][9][lane]) +
                             (red[pe][10][lane] + red[pe][11][lane]);
            const int s = p * SEG + SEG - 1;
            out[(((size_t)b * Ss + s) * Hh + hh) * Dd + lane] = os;
        } else if (wv == 4) {
            const float zs = (red[pe][12][lane] + red[pe][13][lane]) +
                             (red[pe][14][lane] + red[pe][15][lane]);
            zbuf[segbase + (size_t)(SEG - 1) * 64 + lane] = zs;
        }
    }

    float* dst = (mode == 0) ? Gbuf + (size_t)bid * 4096
                             : Mbuf + (size_t)bid * 4096;
#pragma unroll
    for (int r = 0; r < 16; ++r) dst[(r0 + r) * 64 + lane] = h[r];
}

// ---------------------------------------------------------------------------
// Phase 2: SW_p = M_p * SW_{p-1} + G_p, 4 col-blocks per bh.
// XCD-aware mapping: bh = bid & 63 -> the 4 col-blocks of a bh are 64 apart
// in blockIdx (64 % 8 == 0) -> same XCD -> M fetched once per bh.
// ---------------------------------------------------------------------------
template<int NP>
__global__ __launch_bounds__(256) void combine(
    const float* MbufA, const float* MbufB, int nplo, float* __restrict__ Gbuf)
{
    const int bh  = (int)blockIdx.x & (NBH - 1);
    const int cb  = (int)blockIdx.x >> 6;
    const int c0  = cb * 16;
    const int tid = (int)threadIdx.x;
    const int cl  = tid & 15;
    const int c   = c0 + cl;
    const int rg  = tid >> 4;            // 0..15
    const int r0  = rg * 4;
    const int xorv = (rg & 1) << 2;

    __shared__ float4 Ml[2][1024];
    __shared__ __align__(16) float swT[16][68];

    {
        const float* G0 = Gbuf + (size_t)bh * NP * 4096;
        for (int i = tid; i < 1024; i += 256)
            swT[i & 15][i >> 4] = G0[(i >> 4) * 64 + c0 + (i & 15)];
    }

    float4 mreg[4];
    if (NP > 1) {
        const float4* Mp = (const float4*)m_slot((float*)MbufA, (float*)MbufB,
                                                 nplo, bh, 1, NP);
#pragma unroll
        for (int j = 0; j < 4; ++j) mreg[j] = Mp[j * 256 + tid];
    }
    __syncthreads();
#pragma unroll
    for (int j = 0; j < 4; ++j) {
        const int f = j * 256 + tid;
        Ml[0][f ^ ((f >> 4) & 4)] = mreg[j];
    }
    if (NP > 2) {
        const float4* Mp = (const float4*)m_slot((float*)MbufA, (float*)MbufB,
                                                 nplo, bh, 2, NP);
#pragma unroll
        for (int j = 0; j < 4; ++j) mreg[j] = Mp[j * 256 + tid];
    }
    __syncthreads();

    for (int p = 1; p < NP; ++p) {
        const int par = (p - 1) & 1;
        float* Gp = Gbuf + ((size_t)bh * NP + p) * 4096;

        float gacc[4];
#pragma unroll
        for (int r = 0; r < 4; ++r) gacc[r] = Gp[(r0 + r) * 64 + c];

        float accA[4] = {0.f, 0.f, 0.f, 0.f};
        float accB[4] = {0.f, 0.f, 0.f, 0.f};
        const float4* swr = (const float4*)&swT[cl][0];
#pragma unroll
        for (int m4 = 0; m4 < 16; ++m4) {
            const float4 s = swr[m4];
            const int ms = m4 ^ xorv;
#pragma unroll
            for (int r = 0; r < 4; ++r) {
                const float4 m = Ml[par][(r0 + r) * 16 + ms];
                accA[r] = fmaf(m.x, s.x, fmaf(m.y, s.y, accA[r]));
                accB[r] = fmaf(m.z, s.z, fmaf(m.w, s.w, accB[r]));
            }
        }
        __syncthreads();

#pragma unroll
        for (int r = 0; r < 4; ++r) {
            const float val = accA[r] + accB[r] + gacc[r];
            swT[cl][r0 + r] = val;
            Gp[(r0 + r) * 64 + c] = val;
        }
        if (p + 1 < NP) {
#pragma unroll
            for (int j = 0; j < 4; ++j) {
                const int f = j * 256 + tid;
                Ml[par ^ 1][f ^ ((f >> 4) & 4)] = mreg[j];
            }
        }
        if (p + 2 < NP) {
            const float4* Mp = (const float4*)m_slot((float*)MbufA, (float*)MbufB,
                                                     nplo, bh, p + 2, NP);
#pragma unroll
            for (int j = 0; j < 4; ++j) mreg[j] = Mp[j * 256 + tid];
        }
        __syncthreads();
    }
}

// ---------------------------------------------------------------------------
// Phase 3: out[t] += z_t^T SW_{p-1}. One block per (bh, p>=1).
// ---------------------------------------------------------------------------
template<int SEG>
__global__ __launch_bounds__(256) void seg_correct(
    const float* __restrict__ Gbuf, const float* __restrict__ zbuf,
    float* __restrict__ out)
{
    constexpr int NP = Ss / SEG;
    const int bid = (int)blockIdx.x;              // bh*(NP-1) + (p-1)
    const int bh  = bid / (NP - 1);
    const int p   = bid % (NP - 1) + 1;
    const int tid = (int)threadIdx.x;
    const int lane = tid & 63;
    const int w    = tid >> 6;
    const int b = bh >> 5, hh = bh & (Hh - 1);

    __shared__ float SWs[4096];
    __shared__ float zs[SEG * 64];

    const float* sw = Gbuf + ((size_t)bh * NP + p - 1) * 4096;
    const float* zp = zbuf + ((size_t)(bh * NP + p)) * (SEG * 64);
    for (int i = tid; i < 4096; i += 256)
        SWs[i] = sw[i];
    for (int i = tid; i < SEG * 64; i += 256)
        zs[i] = zp[i];
    __syncthreads();

    for (int t = w; t < SEG; t += 4) {
        float a0 = 0.f, a1 = 0.f, a2 = 0.f, a3 = 0.f;
#pragma unroll
        for (int k = 0; k < 64; k += 4) {
            a0 = fmaf(zs[t * 64 + k + 0], SWs[(k + 0) * 64 + lane], a0);
            a1 = fmaf(zs[t * 64 + k + 1], SWs[(k + 1) * 64 + lane], a1);
            a2 = fmaf(zs[t * 64 + k + 2], SWs[(k + 2) * 64 + lane], a2);
            a3 = fmaf(zs[t * 64 + k + 3], SWs[(k + 3) * 64 + lane], a3);
        }
        const int s = p * SEG + t;
        const size_t o = (((size_t)b * Ss + s) * Hh + hh) * Dd + lane;
        out[o] += (a0 + a1) + (a2 + a3);
    }
}

// ---------------------------------------------------------------------------
// FALLBACK kernels (rounds 6/7 proven) for small workspace.
// ---------------------------------------------------------------------------
template<int SEG, int CH>
__global__ __launch_bounds__(512, 6) void scan_seg_fused(
    const float* __restrict__ kp, const float* __restrict__ vp,
    const float* __restrict__ ap, const float* __restrict__ bp,
    const float* __restrict__ gkp,
    float* __restrict__ Gbuf, float* MbufA, float* MbufB, int nplo)
{
    constexpr int NP = Ss / SEG;
    const int tid  = (int)threadIdx.x;
    const int lane = tid & 63;
    const int wv   = __builtin_amdgcn_readfirstlane(tid >> 6);
    const int mode = wv >> 2;
    const int r0   = (wv & 3) << 4;
    const int moff = (wv & 4);
    const int bid  = (int)blockIdx.x;
    const size_t segbase = (size_t)bid * (SEG * Dd);

    __shared__ float la[CH * 64], lb[CH * 64], lw_[CH * 64];
    __shared__ float lk[CH * 64], lv[CH * 64];
    __shared__ float red[2][8][64];

    float h[16];
#pragma unroll
    for (int r = 0; r < 16; ++r) h[r] = mode ? ((r0 + r == lane) ? 1.f : 0.f) : 0.f;

    for (int c0 = 0; c0 < SEG; c0 += CH) {
        __syncthreads();
        {
            const size_t gb = segbase + (size_t)c0 * 64;
            if (tid < CH * 16) {
                ((float4*)la)[tid] = ((const float4*)(ap + gb))[tid];
                ((float4*)lb)[tid] = ((const float4*)(bp + gb))[tid];
                float4 g = ((const float4*)(gkp + gb))[tid], e;
                e.x = __expf(g.x); e.y = __expf(g.y);
                e.z = __expf(g.z); e.w = __expf(g.w);
                ((float4*)lw_)[tid] = e;
            } else {
                const int i2 = tid - CH * 16;
                ((float4*)lk)[i2] = ((const float4*)(kp + gb))[i2];
                ((float4*)lv)[i2] = ((const float4*)(vp + gb))[i2];
            }
        }
        __syncthreads();

#pragma unroll
        for (int tl = 0; tl < CH; ++tl) {
            const int par = (c0 + tl) & 1;
            const float4* ar = (const float4*)(la + tl * 64 + r0);
            float s0 = 0.f, s1 = 0.f, s2 = 0.f, s3 = 0.f;
#pragma unroll
            for (int jj = 0; jj < 4; ++jj) {
                const float4 a4 = ar[jj];
                s0 = fmaf(a4.x, h[4*jj+0], s0);
                s1 = fmaf(a4.y, h[4*jj+1], s1);
                s2 = fmaf(a4.z, h[4*jj+2], s2);
                s3 = fmaf(a4.w, h[4*jj+3], s3);
            }
            red[par][wv][lane] = (s0 + s1) + (s2 + s3);
            __syncthreads();
            const float ah = (red[par][moff + 0][lane] + red[par][moff + 1][lane]) +
                             (red[par][moff + 2][lane] + red[par][moff + 3][lane]);

            const float4* br = (const float4*)(lb  + tl * 64 + r0);
            const float4* wr = (const float4*)(lw_ + tl * 64 + r0);
            if (mode == 0) {
                const float u = lv[tl * 64 + lane];
                const float4* kr = (const float4*)(lk + tl * 64 + r0);
#pragma unroll
                for (int jj = 0; jj < 4; ++jj) {
                    const float4 b4 = br[jj], k4 = kr[jj], w4 = wr[jj];
                    h[4*jj+0] = fmaf(w4.x, h[4*jj+0], fmaf(b4.x, ah, k4.x * u));
                    h[4*jj+1] = fmaf(w4.y, h[4*jj+1], fmaf(b4.y, ah, k4.y * u));
                    h[4*jj+2] = fmaf(w4.z, h[4*jj+2], fmaf(b4.z, ah, k4.z * u));
                    h[4*jj+3] = fmaf(w4.w, h[4*jj+3], fmaf(b4.w, ah, k4.w * u));
                }
            } else {
#pragma unroll
                for (int jj = 0; jj < 4; ++jj) {
                    const float4 b4 = br[jj], w4 = wr[jj];
                    h[4*jj+0] = fmaf(w4.x, h[4*jj+0], b4.x * ah);
                    h[4*jj+1] = fmaf(w4.y, h[4*jj+1], b4.y * ah);
                    h[4*jj+2] = fmaf(w4.z, h[4*jj+2], b4.z * ah);
                    h[4*jj+3] = fmaf(w4.w, h[4*jj+3], b4.w * ah);
                }
            }
        }
    }

    const int p  = bid & (NP - 1);
    const int bh = bid / NP;
    float* dst = (mode == 0) ? Gbuf + (size_t)bid * 4096
                             : m_slot(MbufA, MbufB, nplo, bh, p, NP);
#pragma unroll
    for (int r = 0; r < 16; ++r) dst[(r0 + r) * 64 + lane] = h[r];
}

template<int SEG, int CH>
__global__ __launch_bounds__(256, 6) void scan_out(
    const float* __restrict__ qp, const float* __restrict__ kp,
    const float* __restrict__ vp, const float* __restrict__ ap,
    const float* __restrict__ bp, const float* __restrict__ gkp,
    const float* __restrict__ Gbuf, float* __restrict__ out)
{
    constexpr int NP = Ss / SEG;
    const int tid  = (int)threadIdx.x;
    const int lane = tid & 63;
    const int w    = __builtin_amdgcn_readfirstlane(tid >> 6);
    const int r0   = w << 4;
    const int bid  = (int)blockIdx.x;
    const int p    = bid & (NP - 1);
    const int bh   = bid / NP;
    const int b    = bh >> 5, hh = bh & (Hh - 1);
    const size_t segbase = (size_t)bid * (SEG * Dd);

    __shared__ float la[CH * 64], lb[CH * 64], lw_[CH * 64];
    __shared__ float lk[CH * 64], lv[CH * 64], lq[CH * 64];
    __shared__ float red_a[2][4][64];
    __shared__ float red_o[2][4][64];

    float h[16];
    if (p) {
        const float* sw = Gbuf + (size_t)(bid - 1) * 4096;
#pragma unroll
        for (int r = 0; r < 16; ++r) h[r] = sw[(r0 + r) * 64 + lane];
    } else {
#pragma unroll
        for (int r = 0; r < 16; ++r) h[r] = 0.f;
    }

    for (int c0 = 0; c0 < SEG; c0 += CH) {
        __syncthreads();
        {
            const size_t gb = segbase + (size_t)c0 * 64;
            for (int i = tid; i < CH * 16; i += 256) {
                ((float4*)la)[i] = ((const float4*)(ap + gb))[i];
                ((float4*)lb)[i] = ((const float4*)(bp + gb))[i];
                float4 g = ((const float4*)(gkp + gb))[i], e;
                e.x = __expf(g.x); e.y = __expf(g.y);
                e.z = __expf(g.z); e.w = __expf(g.w);
                ((float4*)lw_)[i] = e;
                ((float4*)lk)[i] = ((const float4*)(kp + gb))[i];
                ((float4*)lv)[i] = ((const float4*)(vp + gb))[i];
                ((float4*)lq)[i] = ((const float4*)(qp + gb))[i];
            }
        }
        __syncthreads();

#pragma unroll
        for (int tl = 0; tl < CH; ++tl) {
            const int t = c0 + tl;
            const int par = t & 1;
            const float4* ar = (const float4*)(la + tl * 64 + r0);
            float s0 = 0.f, s1 = 0.f, s2 = 0.f, s3 = 0.f;
#pragma unroll
            for (int jj = 0; jj < 4; ++jj) {
                const float4 a4 = ar[jj];
                s0 = fmaf(a4.x, h[4*jj+0], s0);
                s1 = fmaf(a4.y, h[4*jj+1], s1);
                s2 = fmaf(a4.z, h[4*jj+2], s2);
                s3 = fmaf(a4.w, h[4*jj+3], s3);
            }
            red_a[par][w][lane] = (s0 + s1) + (s2 + s3);
            __syncthreads();
            const float ah = (red_a[par][0][lane] + red_a[par][1][lane]) +
                             (red_a[par][2][lane] + red_a[par][3][lane]);

            if (w == 0 && t > 0) {
                const int pe = par ^ 1;
                const float os = (red_o[pe][0][lane] + red_o[pe][1][lane]) +
                                 (red_o[pe][2][lane] + red_o[pe][3][lane]);
                const int s = p * SEG + t - 1;
                out[(((size_t)b * Ss + s) * Hh + hh) * Dd + lane] = os;
            }

            const float u = lv[tl * 64 + lane];
            const float4* br = (const float4*)(lb  + tl * 64 + r0);
            const float4* kr = (const float4*)(lk  + tl * 64 + r0);
            const float4* wr = (const float4*)(lw_ + tl * 64 + r0);
            const float4* qr = (const float4*)(lq  + tl * 64 + r0);
            float o0 = 0.f, o1 = 0.f, o2 = 0.f, o3 = 0.f;
#pragma unroll
            for (int jj = 0; jj < 4; ++jj) {
                const float4 b4 = br[jj], k4 = kr[jj], w4 = wr[jj], q4 = qr[jj];
                h[4*jj+0] = fmaf(w4.x, h[4*jj+0], fmaf(b4.x, ah, k4.x * u));
                o0 = fmaf(q4.x, h[4*jj+0], o0);
                h[4*jj+1] = fmaf(w4.y, h[4*jj+1], fmaf(b4.y, ah, k4.y * u));
                o1 = fmaf(q4.y, h[4*jj+1], o1);
                h[4*jj+2] = fmaf(w4.z, h[4*jj+2], fmaf(b4.z, ah, k4.z * u));
                o2 = fmaf(q4.z, h[4*jj+2], o2);
                h[4*jj+3] = fmaf(w4.w, h[4*jj+3], fmaf(b4.w, ah, k4.w * u));
                o3 = fmaf(q4.w, h[4*jj+3], o3);
            }
            red_o[par][w][lane] = (o0 + o1) + (o2 + o3);
        }
    }

    __syncthreads();
    if (w == 0) {
        const int pe = (SEG - 1) & 1;
        const float os = (red_o[pe][0][lane] + red_o[pe][1][lane]) +
                         (red_o[pe][2][lane] + red_o[pe][3][lane]);
        const int s = p * SEG + SEG - 1;
        out[(((size_t)b * Ss + s) * Hh + hh) * Dd + lane] = os;
    }
}

// ---------------------------------------------------------------------------
// Epilogue (unchanged): in-place GroupNorm + correction + gate on d_out.
// ---------------------------------------------------------------------------
__global__ __launch_bounds__(256) void epilogue(
    const float* __restrict__ qp, const float* __restrict__ kp,
    const float* __restrict__ vp, const float* __restrict__ rk,
    const float* __restrict__ gp, const float* __restrict__ sc,
    const float* __restrict__ bi, float* __restrict__ out)
{
    const int lane = (int)(threadIdx.x & 63u);
    const int gid  = (int)blockIdx.x * 4 + (int)(threadIdx.x >> 6);
    const int hh   = gid & (Hh - 1);
    const int bs   = gid >> 5;
    const int b    = bs >> 10;
    const int s    = bs & (Ss - 1);

    const size_t ioff = ((size_t)(b * Hh + hh) * Ss + s) * Dd + lane;
    const float qv = qp[ioff];
    const float kv = kp[ioff];
    const float vv = vp[ioff];
    const float r  = rk[hh * Dd + lane];

    const size_t goff = (size_t)bs * (Hh * Dd) + hh * Dd + lane;
    const float o = out[goff];

    float s1 = o, s2 = o * o, s3 = qv * kv * r;
#pragma unroll
    for (int m = 32; m >= 1; m >>= 1) {
        s1 += __shfl_xor(s1, m, 64);
        s2 += __shfl_xor(s2, m, 64);
        s3 += __shfl_xor(s3, m, 64);
    }
    const float mu  = s1 * (1.f / 64.f);
    const float var = fmaf(-mu, mu, s2 * (1.f / 64.f));
    const float on  = (o - mu) * rsqrtf(var + 1e-5f);

    out[goff] = (fmaf(on, sc[hh * Dd + lane], bi[hh * Dd + lane]) + s3 * vv) * gp[goff];
}

// ---------------------------------------------------------------------------
extern "C" void kernel_launch(void* const* d_in, const int* in_sizes, int n_in,
                              void* d_out, int out_size, void* d_ws, size_t ws_size,
                              hipStream_t stream)
{
    const float* q   = (const float*)d_in[0];
    const float* k   = (const float*)d_in[1];
    const float* v   = (const float*)d_in[2];
    const float* a   = (const float*)d_in[3];
    const float* b   = (const float*)d_in[4];
    const float* gk  = (const float*)d_in[5];
    const float* r_k = (const float*)d_in[6];
    const float* g   = (const float*)d_in[7];
    const float* gns = (const float*)d_in[8];
    const float* gnb = (const float*)d_in[9];
    float* out = (float*)d_out;
    float* ws  = (float*)d_ws;

    // Primary path: SEG=64, NP=16. ws = G + M + z = 50.3 MB.
    const size_t gN  = (size_t)NBH * 16 * 4096;        // floats per G/M/z block
    const size_t need_new = gN * 3 * sizeof(float);
    const size_t g32 = (size_t)NBH * 32 * 4096;
    const size_t need_old32 = g32 * 2 * sizeof(float); // 64 MiB

    if (ws_size >= need_new) {
        float* G = ws;
        float* M = ws + gN;
        float* Z = ws + 2 * gN;
        scan_seg3<64, 16><<<dim3(NBH * 16), dim3(512), 0, stream>>>(
            q, k, v, a, b, gk, G, M, Z, out);
        combine<16><<<dim3(NBH * 4), dim3(256), 0, stream>>>(M, M, 16, G);
        seg_correct<64><<<dim3(NBH * 15), dim3(256), 0, stream>>>(G, Z, out);
    } else if (ws_size >= need_old32) {
        float* G  = ws;
        float* MA = ws + g32;
        scan_seg_fused<32, 16><<<dim3(NBH * 32), dim3(512), 0, stream>>>(
            k, v, a, b, gk, G, MA, MA, 32);
        combine<32><<<dim3(NBH * 4), dim3(256), 0, stream>>>(MA, MA, 32, G);
        scan_out<32, 16><<<dim3(NBH * 32), dim3(256), 0, stream>>>(
            q, k, v, a, b, gk, G, out);
    } else {
        float* G  = ws;
        float* MA = out;
        scan_seg_fused<64, 16><<<dim3(NBH * 16), dim3(512), 0, stream>>>(
            k, v, a, b, gk, G, MA, MA, 16);
        combine<16><<<dim3(NBH * 4), dim3(256), 0, stream>>>(MA, MA, 16, G);
        scan_out<64, 16><<<dim3(NBH * 16), dim3(256), 0, stream>>>(
            q, k, v, a, b, gk, G, out);
    }

    epilogue<<<dim3(Bb * Ss * Hh / 4), dim3(256), 0, stream>>>(
        q, k, v, r_k, g, gns, gnb, out);
}

// Round 10
// 209.948 us; speedup vs baseline: 1.2667x; 1.1536x over previous
//
#include <hip/hip_runtime.h>
#include <hip/hip_bf16.h>

constexpr int Bb = 2, Hh = 32, Ss = 1024, Dd = 64;
constexpr int NBH = Bb * Hh;     // 64

// M-slot indirection for fallback paths.
__device__ __forceinline__ float* m_slot(float* A, float* B, int nplo,
                                         int bh, int p, int np) {
    return (p < nplo) ? A + ((size_t)bh * nplo + p) * 4096
                      : B + ((size_t)bh * (np - nplo) + (p - nplo)) * 4096;
}

// ---------------------------------------------------------------------------
// Phase 1: BARRIER-FREE per-step scan. One 128-thread block per (bh,p):
//   wave 0 (G): h[64] zero-init, input k v^T; per-step o_t = q^T h -> out
//   wave 1 (M): h[64] identity-init, homogeneous; per-step z_t = q^T M -> zbuf
// The full 64-row state is in ONE wave's VGPRs (h[64]); a^T h, the update and
// q^T h are pure in-register FMA chains -- NO per-step barrier, no cross-lane.
// LDS staging of the 6 streams per CH-step chunk (2 barriers / 16 steps),
// broadcast ds_read_b128 with compile-time offsets (step loop fully unrolled).
// ---------------------------------------------------------------------------
template<int SEG, int CH>
__global__ __launch_bounds__(128, 2) void scan_wave(
    const float* __restrict__ qp, const float* __restrict__ kp,
    const float* __restrict__ vp, const float* __restrict__ ap,
    const float* __restrict__ bp, const float* __restrict__ gkp,
    float* __restrict__ Gbuf, float* __restrict__ Mbuf,
    float* __restrict__ zbuf, float* __restrict__ out)
{
    constexpr int NP = Ss / SEG;
    const int tid  = (int)threadIdx.x;
    const int lane = tid & 63;
    const int wv   = __builtin_amdgcn_readfirstlane(tid >> 6);   // 0=G, 1=M
    const int bid  = (int)blockIdx.x;            // bh*NP + p
    const int p    = bid & (NP - 1);
    const int bh   = bid / NP;
    const int b    = bh >> 5, hh = bh & (Hh - 1);
    const size_t segbase = (size_t)bid * (SEG * Dd);

    __shared__ float la[CH * 64], lb[CH * 64], lw_[CH * 64];
    __shared__ float lq[CH * 64], lk[CH * 64], lv[CH * 64];

    float h[64];
#pragma unroll
    for (int j = 0; j < 64; ++j) h[j] = wv ? ((j == lane) ? 1.f : 0.f) : 0.f;

    for (int c0 = 0; c0 < SEG; c0 += CH) {
        __syncthreads();                          // prior chunk LDS reads done
        {
            const size_t gb = segbase + (size_t)c0 * 64;
            const float4* a4 = (const float4*)(ap + gb);
            const float4* b4 = (const float4*)(bp + gb);
            const float4* g4 = (const float4*)(gkp + gb);
            const float4* q4 = (const float4*)(qp + gb);
            const float4* k4 = (const float4*)(kp + gb);
            const float4* v4 = (const float4*)(vp + gb);
#pragma unroll
            for (int i = tid; i < CH * 16; i += 128) {
                ((float4*)la)[i] = a4[i];
                ((float4*)lb)[i] = b4[i];
                float4 g = g4[i], e;
                e.x = __expf(g.x); e.y = __expf(g.y);
                e.z = __expf(g.z); e.w = __expf(g.w);
                ((float4*)lw_)[i] = e;
                ((float4*)lq)[i] = q4[i];
                ((float4*)lk)[i] = k4[i];
                ((float4*)lv)[i] = v4[i];
            }
        }
        __syncthreads();                          // staging visible

#pragma unroll
        for (int tl = 0; tl < CH; ++tl) {
            const int t = c0 + tl;
            // ---- a^T h : 64 in-register FMAs (broadcast b128 reads of a)
            const float4* ar = (const float4*)(la + tl * 64);
            float s0 = 0.f, s1 = 0.f, s2 = 0.f, s3 = 0.f;
#pragma unroll
            for (int jj = 0; jj < 16; ++jj) {
                const float4 a4 = ar[jj];
                s0 = fmaf(a4.x, h[4*jj+0], s0);
                s1 = fmaf(a4.y, h[4*jj+1], s1);
                s2 = fmaf(a4.z, h[4*jj+2], s2);
                s3 = fmaf(a4.w, h[4*jj+3], s3);
            }
            const float ah = (s0 + s1) + (s2 + s3);

            // ---- state update + q^T h (all in-register)
            const float4* br = (const float4*)(lb  + tl * 64);
            const float4* wr = (const float4*)(lw_ + tl * 64);
            const float4* qr = (const float4*)(lq  + tl * 64);
            float o0 = 0.f, o1 = 0.f, o2 = 0.f, o3 = 0.f;
            if (wv == 0) {                        // G wave
                const float u = lv[tl * 64 + lane];
                const float4* kr = (const float4*)(lk + tl * 64);
#pragma unroll
                for (int jj = 0; jj < 16; ++jj) {
                    const float4 b4 = br[jj], k4 = kr[jj], w4 = wr[jj], q4 = qr[jj];
                    h[4*jj+0] = fmaf(w4.x, h[4*jj+0], fmaf(b4.x, ah, k4.x * u));
                    o0 = fmaf(q4.x, h[4*jj+0], o0);
                    h[4*jj+1] = fmaf(w4.y, h[4*jj+1], fmaf(b4.y, ah, k4.y * u));
                    o1 = fmaf(q4.y, h[4*jj+1], o1);
                    h[4*jj+2] = fmaf(w4.z, h[4*jj+2], fmaf(b4.z, ah, k4.z * u));
                    o2 = fmaf(q4.z, h[4*jj+2], o2);
                    h[4*jj+3] = fmaf(w4.w, h[4*jj+3], fmaf(b4.w, ah, k4.w * u));
                    o3 = fmaf(q4.w, h[4*jj+3], o3);
                }
                const int s = p * SEG + t;
                out[(((size_t)b * Ss + s) * Hh + hh) * Dd + lane] =
                    (o0 + o1) + (o2 + o3);
            } else {                              // M wave
#pragma unroll
                for (int jj = 0; jj < 16; ++jj) {
                    const float4 b4 = br[jj], w4 = wr[jj], q4 = qr[jj];
                    h[4*jj+0] = fmaf(w4.x, h[4*jj+0], b4.x * ah);
                    o0 = fmaf(q4.x, h[4*jj+0], o0);
                    h[4*jj+1] = fmaf(w4.y, h[4*jj+1], b4.y * ah);
                    o1 = fmaf(q4.y, h[4*jj+1], o1);
                    h[4*jj+2] = fmaf(w4.z, h[4*jj+2], b4.z * ah);
                    o2 = fmaf(q4.z, h[4*jj+2], o2);
                    h[4*jj+3] = fmaf(w4.w, h[4*jj+3], b4.w * ah);
                    o3 = fmaf(q4.w, h[4*jj+3], o3);
                }
                zbuf[segbase + (size_t)t * 64 + lane] = (o0 + o1) + (o2 + o3);
            }
        }
    }

    float* dst = (wv == 0) ? Gbuf + (size_t)bid * 4096
                           : Mbuf + (size_t)bid * 4096;
#pragma unroll
    for (int j = 0; j < 64; ++j) dst[j * 64 + lane] = h[j];
}

// ---------------------------------------------------------------------------
// Phase 2 (unchanged, proven r8/r9): SW_p = M_p * SW_{p-1} + G_p.
// XCD-aware: bh = bid & 63 -> 4 col-blocks of a bh land on the same XCD.
// ---------------------------------------------------------------------------
template<int NP>
__global__ __launch_bounds__(256) void combine(
    const float* MbufA, const float* MbufB, int nplo, float* __restrict__ Gbuf)
{
    const int bh  = (int)blockIdx.x & (NBH - 1);
    const int cb  = (int)blockIdx.x >> 6;
    const int c0  = cb * 16;
    const int tid = (int)threadIdx.x;
    const int cl  = tid & 15;
    const int c   = c0 + cl;
    const int rg  = tid >> 4;            // 0..15
    const int r0  = rg * 4;
    const int xorv = (rg & 1) << 2;

    __shared__ float4 Ml[2][1024];
    __shared__ __align__(16) float swT[16][68];

    {
        const float* G0 = Gbuf + (size_t)bh * NP * 4096;
        for (int i = tid; i < 1024; i += 256)
            swT[i & 15][i >> 4] = G0[(i >> 4) * 64 + c0 + (i & 15)];
    }

    float4 mreg[4];
    if (NP > 1) {
        const float4* Mp = (const float4*)m_slot((float*)MbufA, (float*)MbufB,
                                                 nplo, bh, 1, NP);
#pragma unroll
        for (int j = 0; j < 4; ++j) mreg[j] = Mp[j * 256 + tid];
    }
    __syncthreads();
#pragma unroll
    for (int j = 0; j < 4; ++j) {
        const int f = j * 256 + tid;
        Ml[0][f ^ ((f >> 4) & 4)] = mreg[j];
    }
    if (NP > 2) {
        const float4* Mp = (const float4*)m_slot((float*)MbufA, (float*)MbufB,
                                                 nplo, bh, 2, NP);
#pragma unroll
        for (int j = 0; j < 4; ++j) mreg[j] = Mp[j * 256 + tid];
    }
    __syncthreads();

    for (int p = 1; p < NP; ++p) {
        const int par = (p - 1) & 1;
        float* Gp = Gbuf + ((size_t)bh * NP + p) * 4096;

        float gacc[4];
#pragma unroll
        for (int r = 0; r < 4; ++r) gacc[r] = Gp[(r0 + r) * 64 + c];

        float accA[4] = {0.f, 0.f, 0.f, 0.f};
        float accB[4] = {0.f, 0.f, 0.f, 0.f};
        const float4* swr = (const float4*)&swT[cl][0];
#pragma unroll
        for (int m4 = 0; m4 < 16; ++m4) {
            const float4 s = swr[m4];
            const int ms = m4 ^ xorv;
#pragma unroll
            for (int r = 0; r < 4; ++r) {
                const float4 m = Ml[par][(r0 + r) * 16 + ms];
                accA[r] = fmaf(m.x, s.x, fmaf(m.y, s.y, accA[r]));
                accB[r] = fmaf(m.z, s.z, fmaf(m.w, s.w, accB[r]));
            }
        }
        __syncthreads();

#pragma unroll
        for (int r = 0; r < 4; ++r) {
            const float val = accA[r] + accB[r] + gacc[r];
            swT[cl][r0 + r] = val;
            Gp[(r0 + r) * 64 + c] = val;
        }
        if (p + 1 < NP) {
#pragma unroll
            for (int j = 0; j < 4; ++j) {
                const int f = j * 256 + tid;
                Ml[par ^ 1][f ^ ((f >> 4) & 4)] = mreg[j];
            }
        }
        if (p + 2 < NP) {
            const float4* Mp = (const float4*)m_slot((float*)MbufA, (float*)MbufB,
                                                     nplo, bh, p + 2, NP);
#pragma unroll
            for (int j = 0; j < 4; ++j) mreg[j] = Mp[j * 256 + tid];
        }
        __syncthreads();
    }
}

// ---------------------------------------------------------------------------
// Phase 3 (unchanged, proven r8/r9): out[t] += z_t^T SW_{p-1}.
// ---------------------------------------------------------------------------
template<int SEG>
__global__ __launch_bounds__(256) void seg_correct(
    const float* __restrict__ Gbuf, const float* __restrict__ zbuf,
    float* __restrict__ out)
{
    constexpr int NP = Ss / SEG;
    const int bid = (int)blockIdx.x;              // bh*(NP-1) + (p-1)
    const int bh  = bid / (NP - 1);
    const int p   = bid % (NP - 1) + 1;
    const int tid = (int)threadIdx.x;
    const int lane = tid & 63;
    const int w    = tid >> 6;
    const int b = bh >> 5, hh = bh & (Hh - 1);

    __shared__ float SWs[4096];
    __shared__ float zs[SEG * 64];

    const float* sw = Gbuf + ((size_t)bh * NP + p - 1) * 4096;
    const float* zp = zbuf + ((size_t)(bh * NP + p)) * (SEG * 64);
    for (int i = tid; i < 4096; i += 256)
        SWs[i] = sw[i];
    for (int i = tid; i < SEG * 64; i += 256)
        zs[i] = zp[i];
    __syncthreads();

    for (int t = w; t < SEG; t += 4) {
        float a0 = 0.f, a1 = 0.f, a2 = 0.f, a3 = 0.f;
#pragma unroll
        for (int k = 0; k < 64; k += 4) {
            a0 = fmaf(zs[t * 64 + k + 0], SWs[(k + 0) * 64 + lane], a0);
            a1 = fmaf(zs[t * 64 + k + 1], SWs[(k + 1) * 64 + lane], a1);
            a2 = fmaf(zs[t * 64 + k + 2], SWs[(k + 2) * 64 + lane], a2);
            a3 = fmaf(zs[t * 64 + k + 3], SWs[(k + 3) * 64 + lane], a3);
        }
        const int s = p * SEG + t;
        const size_t o = (((size_t)b * Ss + s) * Hh + hh) * Dd + lane;
        out[o] += (a0 + a1) + (a2 + a3);
    }
}

// ---------------------------------------------------------------------------
// FALLBACK kernels (rounds 6/7 proven) for small workspace.
// ---------------------------------------------------------------------------
template<int SEG, int CH>
__global__ __launch_bounds__(512, 6) void scan_seg_fused(
    const float* __restrict__ kp, const float* __restrict__ vp,
    const float* __restrict__ ap, const float* __restrict__ bp,
    const float* __restrict__ gkp,
    float* __restrict__ Gbuf, float* MbufA, float* MbufB, int nplo)
{
    constexpr int NP = Ss / SEG;
    const int tid  = (int)threadIdx.x;
    const int lane = tid & 63;
    const int wv   = __builtin_amdgcn_readfirstlane(tid >> 6);
    const int mode = wv >> 2;
    const int r0   = (wv & 3) << 4;
    const int moff = (wv & 4);
    const int bid  = (int)blockIdx.x;
    const size_t segbase = (size_t)bid * (SEG * Dd);

    __shared__ float la[CH * 64], lb[CH * 64], lw_[CH * 64];
    __shared__ float lk[CH * 64], lv[CH * 64];
    __shared__ float red[2][8][64];

    float h[16];
#pragma unroll
    for (int r = 0; r < 16; ++r) h[r] = mode ? ((r0 + r == lane) ? 1.f : 0.f) : 0.f;

    for (int c0 = 0; c0 < SEG; c0 += CH) {
        __syncthreads();
        {
            const size_t gb = segbase + (size_t)c0 * 64;
            if (tid < CH * 16) {
                ((float4*)la)[tid] = ((const float4*)(ap + gb))[tid];
                ((float4*)lb)[tid] = ((const float4*)(bp + gb))[tid];
                float4 g = ((const float4*)(gkp + gb))[tid], e;
                e.x = __expf(g.x); e.y = __expf(g.y);
                e.z = __expf(g.z); e.w = __expf(g.w);
                ((float4*)lw_)[tid] = e;
            } else {
                const int i2 = tid - CH * 16;
                ((float4*)lk)[i2] = ((const float4*)(kp + gb))[i2];
                ((float4*)lv)[i2] = ((const float4*)(vp + gb))[i2];
            }
        }
        __syncthreads();

#pragma unroll
        for (int tl = 0; tl < CH; ++tl) {
            const int par = (c0 + tl) & 1;
            const float4* ar = (const float4*)(la + tl * 64 + r0);
            float s0 = 0.f, s1 = 0.f, s2 = 0.f, s3 = 0.f;
#pragma unroll
            for (int jj = 0; jj < 4; ++jj) {
                const float4 a4 = ar[jj];
                s0 = fmaf(a4.x, h[4*jj+0], s0);
                s1 = fmaf(a4.y, h[4*jj+1], s1);
                s2 = fmaf(a4.z, h[4*jj+2], s2);
                s3 = fmaf(a4.w, h[4*jj+3], s3);
            }
            red[par][wv][lane] = (s0 + s1) + (s2 + s3);
            __syncthreads();
            const float ah = (red[par][moff + 0][lane] + red[par][moff + 1][lane]) +
                             (red[par][moff + 2][lane] + red[par][moff + 3][lane]);

            const float4* br = (const float4*)(lb  + tl * 64 + r0);
            const float4* wr = (const float4*)(lw_ + tl * 64 + r0);
            if (mode == 0) {
                const float u = lv[tl * 64 + lane];
                const float4* kr = (const float4*)(lk + tl * 64 + r0);
#pragma unroll
                for (int jj = 0; jj < 4; ++jj) {
                    const float4 b4 = br[jj], k4 = kr[jj], w4 = wr[jj];
                    h[4*jj+0] = fmaf(w4.x, h[4*jj+0], fmaf(b4.x, ah, k4.x * u));
                    h[4*jj+1] = fmaf(w4.y, h[4*jj+1], fmaf(b4.y, ah, k4.y * u));
                    h[4*jj+2] = fmaf(w4.z, h[4*jj+2], fmaf(b4.z, ah, k4.z * u));
                    h[4*jj+3] = fmaf(w4.w, h[4*jj+3], fmaf(b4.w, ah, k4.w * u));
                }
            } else {
#pragma unroll
                for (int jj = 0; jj < 4; ++jj) {
                    const float4 b4 = br[jj], w4 = wr[jj];
                    h[4*jj+0] = fmaf(w4.x, h[4*jj+0], b4.x * ah);
                    h[4*jj+1] = fmaf(w4.y, h[4*jj+1], b4.y * ah);
                    h[4*jj+2] = fmaf(w4.z, h[4*jj+2], b4.z * ah);
                    h[4*jj+3] = fmaf(w4.w, h[4*jj+3], b4.w * ah);
                }
            }
        }
    }

    const int p  = bid & (NP - 1);
    const int bh = bid / NP;
    float* dst = (mode == 0) ? Gbuf + (size_t)bid * 4096
                             : m_slot(MbufA, MbufB, nplo, bh, p, NP);
#pragma unroll
    for (int r = 0; r < 16; ++r) dst[(r0 + r) * 64 + lane] = h[r];
}

template<int SEG, int CH>
__global__ __launch_bounds__(256, 6) void scan_out(
    const float* __restrict__ qp, const float* __restrict__ kp,
    const float* __restrict__ vp, const float* __restrict__ ap,
    const float* __restrict__ bp, const float* __restrict__ gkp,
    const float* __restrict__ Gbuf, float* __restrict__ out)
{
    constexpr int NP = Ss / SEG;
    const int tid  = (int)threadIdx.x;
    const int lane = tid & 63;
    const int w    = __builtin_amdgcn_readfirstlane(tid >> 6);
    const int r0   = w << 4;
    const int bid  = (int)blockIdx.x;
    const int p    = bid & (NP - 1);
    const int bh   = bid / NP;
    const int b    = bh >> 5, hh = bh & (Hh - 1);
    const size_t segbase = (size_t)bid * (SEG * Dd);

    __shared__ float la[CH * 64], lb[CH * 64], lw_[CH * 64];
    __shared__ float lk[CH * 64], lv[CH * 64], lq[CH * 64];
    __shared__ float red_a[2][4][64];
    __shared__ float red_o[2][4][64];

    float h[16];
    if (p) {
        const float* sw = Gbuf + (size_t)(bid - 1) * 4096;
#pragma unroll
        for (int r = 0; r < 16; ++r) h[r] = sw[(r0 + r) * 64 + lane];
    } else {
#pragma unroll
        for (int r = 0; r < 16; ++r) h[r] = 0.f;
    }

    for (int c0 = 0; c0 < SEG; c0 += CH) {
        __syncthreads();
        {
            const size_t gb = segbase + (size_t)c0 * 64;
            for (int i = tid; i < CH * 16; i += 256) {
                ((float4*)la)[i] = ((const float4*)(ap + gb))[i];
                ((float4*)lb)[i] = ((const float4*)(bp + gb))[i];
                float4 g = ((const float4*)(gkp + gb))[i], e;
                e.x = __expf(g.x); e.y = __expf(g.y);
                e.z = __expf(g.z); e.w = __expf(g.w);
                ((float4*)lw_)[i] = e;
                ((float4*)lk)[i] = ((const float4*)(kp + gb))[i];
                ((float4*)lv)[i] = ((const float4*)(vp + gb))[i];
                ((float4*)lq)[i] = ((const float4*)(qp + gb))[i];
            }
        }
        __syncthreads();

#pragma unroll
        for (int tl = 0; tl < CH; ++tl) {
            const int t = c0 + tl;
            const int par = t & 1;
            const float4* ar = (const float4*)(la + tl * 64 + r0);
            float s0 = 0.f, s1 = 0.f, s2 = 0.f, s3 = 0.f;
#pragma unroll
            for (int jj = 0; jj < 4; ++jj) {
                const float4 a4 = ar[jj];
                s0 = fmaf(a4.x, h[4*jj+0], s0);
                s1 = fmaf(a4.y, h[4*jj+1], s1);
                s2 = fmaf(a4.z, h[4*jj+2], s2);
                s3 = fmaf(a4.w, h[4*jj+3], s3);
            }
            red_a[par][w][lane] = (s0 + s1) + (s2 + s3);
            __syncthreads();
            const float ah = (red_a[par][0][lane] + red_a[par][1][lane]) +
                             (red_a[par][2][lane] + red_a[par][3][lane]);

            if (w == 0 && t > 0) {
                const int pe = par ^ 1;
                const float os = (red_o[pe][0][lane] + red_o[pe][1][lane]) +
                                 (red_o[pe][2][lane] + red_o[pe][3][lane]);
                const int s = p * SEG + t - 1;
                out[(((size_t)b * Ss + s) * Hh + hh) * Dd + lane] = os;
            }

            const float u = lv[tl * 64 + lane];
            const float4* br = (const float4*)(lb  + tl * 64 + r0);
            const float4* kr = (const float4*)(lk  + tl * 64 + r0);
            const float4* wr = (const float4*)(lw_ + tl * 64 + r0);
            const float4* qr = (const float4*)(lq  + tl * 64 + r0);
            float o0 = 0.f, o1 = 0.f, o2 = 0.f, o3 = 0.f;
#pragma unroll
            for (int jj = 0; jj < 4; ++jj) {
                const float4 b4 = br[jj], k4 = kr[jj], w4 = wr[jj], q4 = qr[jj];
                h[4*jj+0] = fmaf(w4.x, h[4*jj+0], fmaf(b4.x, ah, k4.x * u));
                o0 = fmaf(q4.x, h[4*jj+0], o0);
                h[4*jj+1] = fmaf(w4.y, h[4*jj+1], fmaf(b4.y, ah, k4.y * u));
                o1 = fmaf(q4.y, h[4*jj+1], o1);
                h[4*jj+2] = fmaf(w4.z, h[4*jj+2], fmaf(b4.z, ah, k4.z * u));
                o2 = fmaf(q4.z, h[4*jj+2], o2);
                h[4*jj+3] = fmaf(w4.w, h[4*jj+3], fmaf(b4.w, ah, k4.w * u));
                o3 = fmaf(q4.w, h[4*jj+3], o3);
            }
            red_o[par][w][lane] = (o0 + o1) + (o2 + o3);
        }
    }

    __syncthreads();
    if (w == 0) {
        const int pe = (SEG - 1) & 1;
        const float os = (red_o[pe][0][lane] + red_o[pe][1][lane]) +
                         (red_o[pe][2][lane] + red_o[pe][3][lane]);
        const int s = p * SEG + SEG - 1;
        out[(((size_t)b * Ss + s) * Hh + hh) * Dd + lane] = os;
    }
}

// ---------------------------------------------------------------------------
// Epilogue (unchanged): in-place GroupNorm + correction + gate on d_out.
// ---------------------------------------------------------------------------
__global__ __launch_bounds__(256) void epilogue(
    const float* __restrict__ qp, const float* __restrict__ kp,
    const float* __restrict__ vp, const float* __restrict__ rk,
    const float* __restrict__ gp, const float* __restrict__ sc,
    const float* __restrict__ bi, float* __restrict__ out)
{
    const int lane = (int)(threadIdx.x & 63u);
    const int gid  = (int)blockIdx.x * 4 + (int)(threadIdx.x >> 6);
    const int hh   = gid & (Hh - 1);
    const int bs   = gid >> 5;
    const int b    = bs >> 10;
    const int s    = bs & (Ss - 1);

    const size_t ioff = ((size_t)(b * Hh + hh) * Ss + s) * Dd + lane;
    const float qv = qp[ioff];
    const float kv = kp[ioff];
    const float vv = vp[ioff];
    const float r  = rk[hh * Dd + lane];

    const size_t goff = (size_t)bs * (Hh * Dd) + hh * Dd + lane;
    const float o = out[goff];

    float s1 = o, s2 = o * o, s3 = qv * kv * r;
#pragma unroll
    for (int m = 32; m >= 1; m >>= 1) {
        s1 += __shfl_xor(s1, m, 64);
        s2 += __shfl_xor(s2, m, 64);
        s3 += __shfl_xor(s3, m, 64);
    }
    const float mu  = s1 * (1.f / 64.f);
    const float var = fmaf(-mu, mu, s2 * (1.f / 64.f));
    const float on  = (o - mu) * rsqrtf(var + 1e-5f);

    out[goff] = (fmaf(on, sc[hh * Dd + lane], bi[hh * Dd + lane]) + s3 * vv) * gp[goff];
}

// ---------------------------------------------------------------------------
extern "C" void kernel_launch(void* const* d_in, const int* in_sizes, int n_in,
                              void* d_out, int out_size, void* d_ws, size_t ws_size,
                              hipStream_t stream)
{
    const float* q   = (const float*)d_in[0];
    const float* k   = (const float*)d_in[1];
    const float* v   = (const float*)d_in[2];
    const float* a   = (const float*)d_in[3];
    const float* b   = (const float*)d_in[4];
    const float* gk  = (const float*)d_in[5];
    const float* r_k = (const float*)d_in[6];
    const float* g   = (const float*)d_in[7];
    const float* gns = (const float*)d_in[8];
    const float* gnb = (const float*)d_in[9];
    float* out = (float*)d_out;
    float* ws  = (float*)d_ws;

    // Primary path: SEG=64, NP=16. ws = G + M + z = 50.3 MB.
    const size_t gN  = (size_t)NBH * 16 * 4096;        // floats per G/M/z block
    const size_t need_new = gN * 3 * sizeof(float);
    const size_t g32 = (size_t)NBH * 32 * 4096;
    const size_t need_old32 = g32 * 2 * sizeof(float); // 64 MiB

    if (ws_size >= need_new) {
        float* G = ws;
        float* M = ws + gN;
        float* Z = ws + 2 * gN;
        scan_wave<64, 16><<<dim3(NBH * 16), dim3(128), 0, stream>>>(
            q, k, v, a, b, gk, G, M, Z, out);
        combine<16><<<dim3(NBH * 4), dim3(256), 0, stream>>>(M, M, 16, G);
        seg_correct<64><<<dim3(NBH * 15), dim3(256), 0, stream>>>(G, Z, out);
    } else if (ws_size >= need_old32) {
        float* G  = ws;
        float* MA = ws + g32;
        scan_seg_fused<32, 16><<<dim3(NBH * 32), dim3(512), 0, stream>>>(
            k, v, a, b, gk, G, MA, MA, 32);
        combine<32><<<dim3(NBH * 4), dim3(256), 0, stream>>>(MA, MA, 32, G);
        scan_out<32, 16><<<dim3(NBH * 32), dim3(256), 0, stream>>>(
            q, k, v, a, b, gk, G, out);
    } else {
        float* G  = ws;
        float* MA = out;
        scan_seg_fused<64, 16><<<dim3(NBH * 16), dim3(512), 0, stream>>>(
            k, v, a, b, gk, G, MA, MA, 16);
        combine<16><<<dim3(NBH * 4), dim3(256), 0, stream>>>(MA, MA, 16, G);
        scan_out<64, 16><<<dim3(NBH * 16), dim3(256), 0, stream>>>(
            q, k, v, a, b, gk, G, out);
    }

    epilogue<<<dim3(Bb * Ss * Hh / 4), dim3(256), 0, stream>>>(
        q, k, v, r_k, g, gns, gnb, out);
}